// Round 1
// baseline (1280.398 us; speedup 1.0000x reference)
//
#include <hip/hip_runtime.h>

namespace {

constexpr int kN  = 20000;
constexpr int kE  = 80000;
constexpr int kIn = 64;
constexpr int kH  = 32;
constexpr int kEA = 32;
constexpr int kT  = 64;
constexpr int kL  = 3;
constexpr float kEps = 1e-5f;
constexpr int OCH = 8;  // output-channel chunk in edge kernel

// ---------------- h = x @ initW + initb ----------------
__global__ __launch_bounds__(64) void init_proj(
    const float* __restrict__ x, const float* __restrict__ W,
    const float* __restrict__ b, float* __restrict__ h) {
  __shared__ float Wl[kIn * kH];
  __shared__ float bl[kH];
  const int tid = threadIdx.x;
  for (int j = tid; j < kIn * kH; j += 64) Wl[j] = W[j];
  if (tid < kH) bl[tid] = b[tid];
  __syncthreads();
  const int node = blockIdx.x * 64 + tid;
  if (node >= kN) return;
  float xr[kIn];
  const float4* xp = reinterpret_cast<const float4*>(x + (size_t)node * kIn);
#pragma unroll
  for (int k4 = 0; k4 < kIn / 4; ++k4) {
    float4 v = xp[k4];
    xr[k4 * 4 + 0] = v.x; xr[k4 * 4 + 1] = v.y;
    xr[k4 * 4 + 2] = v.z; xr[k4 * 4 + 3] = v.w;
  }
  float* hp = h + (size_t)node * kH;
  for (int o = 0; o < kH; ++o) {
    float acc = bl[o];
#pragma unroll
    for (int k = 0; k < kIn; ++k) acc = fmaf(xr[k], Wl[k * kH + o], acc);
    hp[o] = acc;
  }
}

// ------------- fused edge MLP + message + scatter-add -------------
// per edge e: ew[i][o] = relu(sum_a attr[e][a]*Wm[a][i*H+o] + bm[i*H+o])
//             msg[o]  = sum_i h[src][i]*ew[i][o];  agg[dst][o] += msg[o]
__global__ __launch_bounds__(256) void edge_msg(
    const float* __restrict__ attr, const int* __restrict__ ei,
    const float* __restrict__ h, const float* __restrict__ Wm,
    const float* __restrict__ bm, float* __restrict__ agg) {
  __shared__ float wl[kEA * kH * OCH];  // 32 KB : [(a*kH+i)*OCH + t]
  __shared__ float bml[kH * kH];        // 4 KB
  const int tid = threadIdx.x;
  for (int j = tid; j < kH * kH; j += 256) bml[j] = bm[j];
  const int e = blockIdx.x * 256 + tid;
  const bool act = e < kE;
  float at[kEA];
  int src = 0, dst = 0;
  if (act) {
    const float4* ap = reinterpret_cast<const float4*>(attr + (size_t)e * kEA);
#pragma unroll
    for (int a4 = 0; a4 < kEA / 4; ++a4) {
      float4 v = ap[a4];
      at[a4 * 4 + 0] = v.x; at[a4 * 4 + 1] = v.y;
      at[a4 * 4 + 2] = v.z; at[a4 * 4 + 3] = v.w;
    }
    src = ei[e];
    dst = ei[kE + e];
  } else {
#pragma unroll
    for (int a = 0; a < kEA; ++a) at[a] = 0.f;
  }
  const float* hrow = h + (size_t)src * kH;

  for (int oc = 0; oc < kH / OCH; ++oc) {
    __syncthreads();
    // stage Wm[:, :, oc*8 .. +7] into LDS
    for (int j = tid; j < kEA * kH; j += 256) {
      const float* ws = Wm + (size_t)j * kH + oc * OCH;  // j = a*kH+i (row a, col i*kH)
      float4 v0 = *reinterpret_cast<const float4*>(ws);
      float4 v1 = *reinterpret_cast<const float4*>(ws + 4);
      *reinterpret_cast<float4*>(wl + j * OCH) = v0;
      *reinterpret_cast<float4*>(wl + j * OCH + 4) = v1;
    }
    __syncthreads();
    float mo[OCH];
#pragma unroll
    for (int t = 0; t < OCH; ++t) mo[t] = 0.f;
    for (int i = 0; i < kH; ++i) {
      float ew[OCH];
      const float* bp = bml + i * kH + oc * OCH;
#pragma unroll
      for (int t = 0; t < OCH; ++t) ew[t] = bp[t];
#pragma unroll
      for (int a = 0; a < kEA; ++a) {
        const float av = at[a];
        const float* wpa = wl + (a * kH + i) * OCH;
#pragma unroll
        for (int t = 0; t < OCH; ++t) ew[t] = fmaf(av, wpa[t], ew[t]);
      }
      const float hi = hrow[i];
#pragma unroll
      for (int t = 0; t < OCH; ++t)
        mo[t] = fmaf(hi, fmaxf(ew[t], 0.f), mo[t]);
    }
    if (act) {
      float* ap2 = agg + (size_t)dst * kH + oc * OCH;
#pragma unroll
      for (int t = 0; t < OCH; ++t) atomicAdd(ap2 + t, mo[t]);
    }
  }
}

// ------- conv = agg + h@rootW + rootb (in place on agg) + feature stats -------
__global__ __launch_bounds__(64) void root_stats(
    const float* __restrict__ h, const float* __restrict__ W,
    const float* __restrict__ b, float* __restrict__ conv,
    float* __restrict__ stats) {
  __shared__ float Wl[kH * kH];
  __shared__ float bl[kH];
  const int tid = threadIdx.x;
  for (int j = tid; j < kH * kH; j += 64) Wl[j] = W[j];
  if (tid < kH) bl[tid] = b[tid];
  __syncthreads();
  const int node = blockIdx.x * 64 + tid;
  const bool act = node < kN;
  float hr[kH];
  if (act) {
    const float* hp = h + (size_t)node * kH;
#pragma unroll
    for (int i = 0; i < kH; ++i) hr[i] = hp[i];
  } else {
#pragma unroll
    for (int i = 0; i < kH; ++i) hr[i] = 0.f;
  }
  float* cp = conv + (size_t)node * kH;
  for (int o = 0; o < kH; ++o) {
    float acc = 0.f;
    if (act) {
      acc = cp[o] + bl[o];
#pragma unroll
      for (int i = 0; i < kH; ++i) acc = fmaf(hr[i], Wl[i * kH + o], acc);
      cp[o] = acc;
    }
    float s = acc, q = acc * acc;
#pragma unroll
    for (int d = 1; d < 64; d <<= 1) {
      s += __shfl_xor(s, d);
      q += __shfl_xor(q, d);
    }
    if (tid == 0) {
      atomicAdd(stats + o, s);
      atomicAdd(stats + kH + o, q);
    }
  }
}

// ---- hc = relu(graphnorm(conv))+h ; h = relu([h,hc] @ transW + transb) ----
__global__ __launch_bounds__(64) void norm_trans(
    const float* __restrict__ conv, const float* __restrict__ stats,
    const float* __restrict__ gw, const float* __restrict__ gb,
    const float* __restrict__ gms, const float* __restrict__ Wt,
    const float* __restrict__ tb, float* __restrict__ h) {
  __shared__ float Wl[2 * kH * kH];
  __shared__ float tbl[kH];
  __shared__ float meanl[kH], rstdl[kH], gwl[kH], gbl[kH];
  const int tid = threadIdx.x;
  for (int j = tid; j < 2 * kH * kH; j += 64) Wl[j] = Wt[j];
  if (tid < kH) {
    tbl[tid] = tb[tid];
    float m = stats[tid] * (1.f / kN);
    float q = stats[kH + tid] * (1.f / kN);
    float msv = gms[tid];
    float var = q - m * m * msv * (2.f - msv);
    meanl[tid] = msv * m;
    rstdl[tid] = rsqrtf(var + kEps);
    gwl[tid] = gw[tid];
    gbl[tid] = gb[tid];
  }
  __syncthreads();
  const int node = blockIdx.x * 64 + tid;
  if (node >= kN) return;
  float in_[2 * kH];
  const float* hp = h + (size_t)node * kH;
  const float* cp = conv + (size_t)node * kH;
#pragma unroll
  for (int i = 0; i < kH; ++i) in_[i] = hp[i];
#pragma unroll
  for (int o = 0; o < kH; ++o) {
    float v = cp[o];
    float hc = fmaxf((v - meanl[o]) * rstdl[o] * gwl[o] + gbl[o], 0.f) + in_[o];
    in_[kH + o] = hc;
  }
  float* hw = h + (size_t)node * kH;
  for (int o = 0; o < kH; ++o) {
    float acc = tbl[o];
#pragma unroll
    for (int k = 0; k < 2 * kH; ++k) acc = fmaf(in_[k], Wl[k * kH + o], acc);
    hw[o] = fmaxf(acc, 0.f);
  }
}

// ---------- out = h @ finalW + finalb  (+ stats over kT feats) ----------
__global__ __launch_bounds__(64) void final_lin(
    const float* __restrict__ h, const float* __restrict__ W,
    const float* __restrict__ b, float* __restrict__ out,
    float* __restrict__ stats) {
  __shared__ float Wl[kH * kT];
  __shared__ float bl[kT];
  const int tid = threadIdx.x;
  for (int j = tid; j < kH * kT; j += 64) Wl[j] = W[j];
  if (tid < kT) bl[tid] = b[tid];
  __syncthreads();
  const int node = blockIdx.x * 64 + tid;
  const bool act = node < kN;
  float hr[kH];
  if (act) {
    const float* hp = h + (size_t)node * kH;
#pragma unroll
    for (int i = 0; i < kH; ++i) hr[i] = hp[i];
  } else {
#pragma unroll
    for (int i = 0; i < kH; ++i) hr[i] = 0.f;
  }
  float* op = out + (size_t)node * kT;
  for (int o = 0; o < kT; ++o) {
    float acc = 0.f;
    if (act) {
      acc = bl[o];
#pragma unroll
      for (int i = 0; i < kH; ++i) acc = fmaf(hr[i], Wl[i * kT + o], acc);
      op[o] = acc;
    }
    float s = acc, q = acc * acc;
#pragma unroll
    for (int d = 1; d < 64; d <<= 1) {
      s += __shfl_xor(s, d);
      q += __shfl_xor(q, d);
    }
    if (tid == 0) {
      atomicAdd(stats + o, s);
      atomicAdd(stats + kT + o, q);
    }
  }
}

// ---------------- final graphnorm + relu (in place on out) ----------------
__global__ __launch_bounds__(64) void final_norm(
    const float* __restrict__ stats, const float* __restrict__ w,
    const float* __restrict__ b, const float* __restrict__ ms,
    float* __restrict__ out) {
  __shared__ float meanl[kT], rstdl[kT], wl2[kT], bl2[kT];
  const int tid = threadIdx.x;
  {
    float m = stats[tid] * (1.f / kN);
    float q = stats[kT + tid] * (1.f / kN);
    float msv = ms[tid];
    float var = q - m * m * msv * (2.f - msv);
    meanl[tid] = msv * m;
    rstdl[tid] = rsqrtf(var + kEps);
    wl2[tid] = w[tid];
    bl2[tid] = b[tid];
  }
  __syncthreads();
  const int node = blockIdx.x * 64 + tid;
  if (node >= kN) return;
  float* op = out + (size_t)node * kT;
  for (int o = 0; o < kT; ++o) {
    float v = op[o];
    op[o] = fmaxf((v - meanl[o]) * rstdl[o] * wl2[o] + bl2[o], 0.f);
  }
}

}  // namespace

extern "C" void kernel_launch(void* const* d_in, const int* in_sizes, int n_in,
                              void* d_out, int out_size, void* d_ws,
                              size_t ws_size, hipStream_t stream) {
  const float* x     = (const float*)d_in[0];
  const float* eattr = (const float*)d_in[1];
  const int*   eidx  = (const int*)d_in[2];
  const float* initW = (const float*)d_in[3];
  const float* initb = (const float*)d_in[4];
  const float* emW   = (const float*)d_in[5];
  const float* emb   = (const float*)d_in[6];
  const float* rW    = (const float*)d_in[7];
  const float* rb    = (const float*)d_in[8];
  const float* gnw   = (const float*)d_in[9];
  const float* gnb   = (const float*)d_in[10];
  const float* gnms  = (const float*)d_in[11];
  const float* tW    = (const float*)d_in[12];
  const float* tb    = (const float*)d_in[13];
  const float* fW    = (const float*)d_in[14];
  const float* fb    = (const float*)d_in[15];
  const float* fgw   = (const float*)d_in[16];
  const float* fgb   = (const float*)d_in[17];
  const float* fgms  = (const float*)d_in[18];
  float* out = (float*)d_out;

  float* h     = (float*)d_ws;                 // kN*kH
  float* conv  = h + (size_t)kN * kH;          // kN*kH (agg then conv, in place)
  float* stats = conv + (size_t)kN * kH;       // 128 floats

  const int nodeBlocks = (kN + 63) / 64;       // 313
  const int edgeBlocks = (kE + 255) / 256;     // 313

  init_proj<<<nodeBlocks, 64, 0, stream>>>(x, initW, initb, h);
  for (int l = 0; l < kL; ++l) {
    hipMemsetAsync(conv, 0, (size_t)kN * kH * sizeof(float), stream);
    edge_msg<<<edgeBlocks, 256, 0, stream>>>(
        eattr, eidx, h, emW + (size_t)l * kEA * kH * kH,
        emb + (size_t)l * kH * kH, conv);
    hipMemsetAsync(stats, 0, 2 * kH * sizeof(float), stream);
    root_stats<<<nodeBlocks, 64, 0, stream>>>(
        h, rW + (size_t)l * kH * kH, rb + l * kH, conv, stats);
    norm_trans<<<nodeBlocks, 64, 0, stream>>>(
        conv, stats, gnw + l * kH, gnb + l * kH, gnms + l * kH,
        tW + (size_t)l * 2 * kH * kH, tb + l * kH, h);
  }
  hipMemsetAsync(stats, 0, 2 * kT * sizeof(float), stream);
  final_lin<<<nodeBlocks, 64, 0, stream>>>(h, fW, fb, out, stats);
  final_norm<<<nodeBlocks, 64, 0, stream>>>(stats, fgw, fgb, fgms, out);
}

// Round 2
// 705.912 us; speedup vs baseline: 1.8138x; 1.8138x over previous
//
#include <hip/hip_runtime.h>

namespace {

constexpr int kN  = 20000;
constexpr int kE  = 80000;
constexpr int kIn = 64;
constexpr int kH  = 32;
constexpr int kEA = 32;
constexpr int kT  = 64;
constexpr int kL  = 3;
constexpr float kEps = 1e-5f;
constexpr int OCH = 8;  // output-channel chunk in edge kernel (4 chunks via blockIdx.y)

// ---------------- h = x @ initW + initb ----------------
__global__ __launch_bounds__(256) void init_proj(
    const float* __restrict__ x, const float* __restrict__ W,
    const float* __restrict__ b, float* __restrict__ h) {
  __shared__ float Wl[kIn * kH];  // 8 KB
  __shared__ float bl[kH];
  const int tid = threadIdx.x;
  for (int j = tid; j < kIn * kH; j += 256) Wl[j] = W[j];
  if (tid < kH) bl[tid] = b[tid];
  __syncthreads();
  const int node = blockIdx.x * 256 + tid;
  if (node >= kN) return;
  float xr[kIn];
  const float4* xp = reinterpret_cast<const float4*>(x + (size_t)node * kIn);
#pragma unroll
  for (int k4 = 0; k4 < kIn / 4; ++k4) {
    float4 v = xp[k4];
    xr[k4 * 4 + 0] = v.x; xr[k4 * 4 + 1] = v.y;
    xr[k4 * 4 + 2] = v.z; xr[k4 * 4 + 3] = v.w;
  }
  float* hp = h + (size_t)node * kH;
#pragma unroll
  for (int o = 0; o < kH; ++o) {
    float acc = bl[o];
#pragma unroll
    for (int k = 0; k < kIn; ++k) acc = fmaf(xr[k], Wl[k * kH + o], acc);
    hp[o] = acc;
  }
}

// ------------- fused edge MLP + message + scatter-add -------------
// grid (ceil(E/256), 4): blockIdx.y = output-channel chunk oc (8 outputs each)
__global__ __launch_bounds__(256) void edge_msg(
    const float* __restrict__ attr, const int* __restrict__ ei,
    const float* __restrict__ h, const float* __restrict__ Wm,
    const float* __restrict__ bm, float* __restrict__ agg) {
  __shared__ float wl[kEA * kH * OCH];  // 32 KB : [(a*kH+i)*OCH + t]
  __shared__ float bml[kH * OCH];       // 1 KB
  const int tid = threadIdx.x;
  const int oc = blockIdx.y;
  // stage W slice [:, :, oc*8 .. +7]
  for (int j = tid; j < kEA * kH; j += 256) {
    const float* ws = Wm + (size_t)j * kH + oc * OCH;  // j = a*kH + i
    float4 v0 = *reinterpret_cast<const float4*>(ws);
    float4 v1 = *reinterpret_cast<const float4*>(ws + 4);
    *reinterpret_cast<float4*>(wl + j * OCH) = v0;
    *reinterpret_cast<float4*>(wl + j * OCH + 4) = v1;
  }
  {  // bias slice: 256 threads == 32*8 elements exactly
    const int i = tid >> 3, t = tid & 7;
    bml[tid] = bm[i * kH + oc * OCH + t];
  }
  const int e = blockIdx.x * 256 + tid;
  const bool act = e < kE;
  float at[kEA];
  int src = 0, dst = 0;
  if (act) {
    const float4* ap = reinterpret_cast<const float4*>(attr + (size_t)e * kEA);
#pragma unroll
    for (int a4 = 0; a4 < kEA / 4; ++a4) {
      float4 v = ap[a4];
      at[a4 * 4 + 0] = v.x; at[a4 * 4 + 1] = v.y;
      at[a4 * 4 + 2] = v.z; at[a4 * 4 + 3] = v.w;
    }
    src = ei[e];
    dst = ei[kE + e];
  } else {
#pragma unroll
    for (int a = 0; a < kEA; ++a) at[a] = 0.f;
  }
  float hr[kH];
  {
    const float4* hp = reinterpret_cast<const float4*>(h + (size_t)src * kH);
#pragma unroll
    for (int i4 = 0; i4 < kH / 4; ++i4) {
      float4 v = hp[i4];
      hr[i4 * 4 + 0] = v.x; hr[i4 * 4 + 1] = v.y;
      hr[i4 * 4 + 2] = v.z; hr[i4 * 4 + 3] = v.w;
    }
  }
  __syncthreads();
  float mo[OCH];
#pragma unroll
  for (int t = 0; t < OCH; ++t) mo[t] = 0.f;
  for (int i = 0; i < kH; ++i) {
    float ew[OCH];
    const float* bp = bml + i * OCH;
#pragma unroll
    for (int t = 0; t < OCH; ++t) ew[t] = bp[t];
#pragma unroll
    for (int a = 0; a < kEA; ++a) {
      const float av = at[a];
      const float* wpa = wl + (a * kH + i) * OCH;
#pragma unroll
      for (int t = 0; t < OCH; ++t) ew[t] = fmaf(av, wpa[t], ew[t]);
    }
    const float hi = hr[i];
#pragma unroll
    for (int t = 0; t < OCH; ++t)
      mo[t] = fmaf(hi, fmaxf(ew[t], 0.f), mo[t]);
  }
  if (act) {
    float* ap2 = agg + (size_t)dst * kH + oc * OCH;
#pragma unroll
    for (int t = 0; t < OCH; ++t) atomicAdd(ap2 + t, mo[t]);
  }
}

// ------- conv = agg + h@rootW + rootb (in place on agg) + feature stats -------
__global__ __launch_bounds__(256) void root_stats(
    const float* __restrict__ h, const float* __restrict__ W,
    const float* __restrict__ b, float* __restrict__ conv,
    float* __restrict__ stats) {
  __shared__ float Wl[kH * kH];        // 4 KB
  __shared__ float bl[kH];
  __shared__ float buf[256 * (kH + 1)];  // 33 KB, padded stride 33
  const int tid = threadIdx.x;
  for (int j = tid; j < kH * kH; j += 256) Wl[j] = W[j];
  if (tid < kH) bl[tid] = b[tid];
  __syncthreads();
  const int node = blockIdx.x * 256 + tid;
  const bool act = node < kN;
  float hr[kH];
  if (act) {
    const float4* hp = reinterpret_cast<const float4*>(h + (size_t)node * kH);
#pragma unroll
    for (int i4 = 0; i4 < kH / 4; ++i4) {
      float4 v = hp[i4];
      hr[i4 * 4 + 0] = v.x; hr[i4 * 4 + 1] = v.y;
      hr[i4 * 4 + 2] = v.z; hr[i4 * 4 + 3] = v.w;
    }
  } else {
#pragma unroll
    for (int i = 0; i < kH; ++i) hr[i] = 0.f;
  }
  float* cp = conv + (size_t)node * kH;
#pragma unroll
  for (int o = 0; o < kH; ++o) {
    float acc = 0.f;
    if (act) {
      acc = cp[o] + bl[o];
#pragma unroll
      for (int i = 0; i < kH; ++i) acc = fmaf(hr[i], Wl[i * kH + o], acc);
      cp[o] = acc;
    }
    buf[tid * (kH + 1) + o] = act ? acc : 0.f;
  }
  __syncthreads();
  if (tid < kH) {
    float s = 0.f, q = 0.f;
#pragma unroll 8
    for (int r = 0; r < 256; ++r) {
      float v = buf[r * (kH + 1) + tid];
      s += v;
      q = fmaf(v, v, q);
    }
    atomicAdd(stats + tid, s);
    atomicAdd(stats + kH + tid, q);
  }
}

// ---- hc = relu(graphnorm(conv))+h ; h = relu([h,hc] @ transW + transb) ----
__global__ __launch_bounds__(256) void norm_trans(
    const float* __restrict__ conv, const float* __restrict__ stats,
    const float* __restrict__ gw, const float* __restrict__ gb,
    const float* __restrict__ gms, const float* __restrict__ Wt,
    const float* __restrict__ tb, float* __restrict__ h) {
  __shared__ float Wl[2 * kH * kH];  // 8 KB
  __shared__ float tbl[kH];
  __shared__ float meanl[kH], rstdl[kH], gwl[kH], gbl[kH];
  const int tid = threadIdx.x;
  for (int j = tid; j < 2 * kH * kH; j += 256) Wl[j] = Wt[j];
  if (tid < kH) {
    tbl[tid] = tb[tid];
    float m = stats[tid] * (1.f / kN);
    float q = stats[kH + tid] * (1.f / kN);
    float msv = gms[tid];
    float var = q - m * m * msv * (2.f - msv);
    meanl[tid] = msv * m;
    rstdl[tid] = rsqrtf(var + kEps);
    gwl[tid] = gw[tid];
    gbl[tid] = gb[tid];
  }
  __syncthreads();
  const int node = blockIdx.x * 256 + tid;
  if (node >= kN) return;
  float in_[2 * kH];
  const float* hp = h + (size_t)node * kH;
  const float* cp = conv + (size_t)node * kH;
#pragma unroll
  for (int i = 0; i < kH; ++i) in_[i] = hp[i];
#pragma unroll
  for (int o = 0; o < kH; ++o) {
    float v = cp[o];
    in_[kH + o] =
        fmaxf((v - meanl[o]) * rstdl[o] * gwl[o] + gbl[o], 0.f) + in_[o];
  }
  float* hw = h + (size_t)node * kH;
#pragma unroll
  for (int o = 0; o < kH; ++o) {
    float acc = tbl[o];
#pragma unroll
    for (int k = 0; k < 2 * kH; ++k) acc = fmaf(in_[k], Wl[k * kH + o], acc);
    hw[o] = fmaxf(acc, 0.f);
  }
}

// ---------- out = h @ finalW + finalb  (+ stats over kT feats) ----------
__global__ __launch_bounds__(256) void final_lin(
    const float* __restrict__ h, const float* __restrict__ W,
    const float* __restrict__ b, float* __restrict__ out,
    float* __restrict__ stats) {
  __shared__ float Wl[kH * kT];  // 8 KB
  __shared__ float bl[kT];
  __shared__ float buf[256 * (kT + 1)];  // 65 KB, padded stride 65
  const int tid = threadIdx.x;
  for (int j = tid; j < kH * kT; j += 256) Wl[j] = W[j];
  if (tid < kT) bl[tid] = b[tid];
  __syncthreads();
  const int node = blockIdx.x * 256 + tid;
  const bool act = node < kN;
  float hr[kH];
  if (act) {
    const float4* hp = reinterpret_cast<const float4*>(h + (size_t)node * kH);
#pragma unroll
    for (int i4 = 0; i4 < kH / 4; ++i4) {
      float4 v = hp[i4];
      hr[i4 * 4 + 0] = v.x; hr[i4 * 4 + 1] = v.y;
      hr[i4 * 4 + 2] = v.z; hr[i4 * 4 + 3] = v.w;
    }
  } else {
#pragma unroll
    for (int i = 0; i < kH; ++i) hr[i] = 0.f;
  }
  float* op = out + (size_t)node * kT;
#pragma unroll
  for (int o = 0; o < kT; ++o) {
    float acc = 0.f;
    if (act) {
      acc = bl[o];
#pragma unroll
      for (int i = 0; i < kH; ++i) acc = fmaf(hr[i], Wl[i * kT + o], acc);
      op[o] = acc;
    }
    buf[tid * (kT + 1) + o] = act ? acc : 0.f;
  }
  __syncthreads();
  if (tid < kT) {
    float s = 0.f, q = 0.f;
#pragma unroll 8
    for (int r = 0; r < 256; ++r) {
      float v = buf[r * (kT + 1) + tid];
      s += v;
      q = fmaf(v, v, q);
    }
    atomicAdd(stats + tid, s);
    atomicAdd(stats + kT + tid, q);
  }
}

// ---------------- final graphnorm + relu (in place on out) ----------------
__global__ __launch_bounds__(256) void final_norm(
    const float* __restrict__ stats, const float* __restrict__ w,
    const float* __restrict__ b, const float* __restrict__ ms,
    float* __restrict__ out) {
  __shared__ float meanl[kT], rstdl[kT], wl2[kT], bl2[kT];
  const int tid = threadIdx.x;
  if (tid < kT) {
    float m = stats[tid] * (1.f / kN);
    float q = stats[kT + tid] * (1.f / kN);
    float msv = ms[tid];
    float var = q - m * m * msv * (2.f - msv);
    meanl[tid] = msv * m;
    rstdl[tid] = rsqrtf(var + kEps);
    wl2[tid] = w[tid];
    bl2[tid] = b[tid];
  }
  __syncthreads();
  const int node = blockIdx.x * 256 + tid;
  if (node >= kN) return;
  float* op = out + (size_t)node * kT;
#pragma unroll
  for (int o4 = 0; o4 < kT / 4; ++o4) {
    float4 v = *reinterpret_cast<const float4*>(op + o4 * 4);
    float r[4] = {v.x, v.y, v.z, v.w};
#pragma unroll
    for (int j = 0; j < 4; ++j) {
      int o = o4 * 4 + j;
      r[j] = fmaxf((r[j] - meanl[o]) * rstdl[o] * wl2[o] + bl2[o], 0.f);
    }
    *reinterpret_cast<float4*>(op + o4 * 4) =
        make_float4(r[0], r[1], r[2], r[3]);
  }
}

}  // namespace

extern "C" void kernel_launch(void* const* d_in, const int* in_sizes, int n_in,
                              void* d_out, int out_size, void* d_ws,
                              size_t ws_size, hipStream_t stream) {
  const float* x     = (const float*)d_in[0];
  const float* eattr = (const float*)d_in[1];
  const int*   eidx  = (const int*)d_in[2];
  const float* initW = (const float*)d_in[3];
  const float* initb = (const float*)d_in[4];
  const float* emW   = (const float*)d_in[5];
  const float* emb   = (const float*)d_in[6];
  const float* rW    = (const float*)d_in[7];
  const float* rb    = (const float*)d_in[8];
  const float* gnw   = (const float*)d_in[9];
  const float* gnb   = (const float*)d_in[10];
  const float* gnms  = (const float*)d_in[11];
  const float* tW    = (const float*)d_in[12];
  const float* tb    = (const float*)d_in[13];
  const float* fW    = (const float*)d_in[14];
  const float* fb    = (const float*)d_in[15];
  const float* fgw   = (const float*)d_in[16];
  const float* fgb   = (const float*)d_in[17];
  const float* fgms  = (const float*)d_in[18];
  float* out = (float*)d_out;

  float* h     = (float*)d_ws;                 // kN*kH
  float* conv  = h + (size_t)kN * kH;          // kN*kH (agg then conv in place)
  float* stats = conv + (size_t)kN * kH;       // 128 floats

  const int nodeBlocks = (kN + 255) / 256;     // 79
  const dim3 edgeGrid((kE + 255) / 256, kH / OCH);  // 313 x 4

  init_proj<<<nodeBlocks, 256, 0, stream>>>(x, initW, initb, h);
  for (int l = 0; l < kL; ++l) {
    hipMemsetAsync(conv, 0, (size_t)kN * kH * sizeof(float), stream);
    edge_msg<<<edgeGrid, 256, 0, stream>>>(
        eattr, eidx, h, emW + (size_t)l * kEA * kH * kH,
        emb + (size_t)l * kH * kH, conv);
    hipMemsetAsync(stats, 0, 2 * kH * sizeof(float), stream);
    root_stats<<<nodeBlocks, 256, 0, stream>>>(
        h, rW + (size_t)l * kH * kH, rb + l * kH, conv, stats);
    norm_trans<<<nodeBlocks, 256, 0, stream>>>(
        conv, stats, gnw + l * kH, gnb + l * kH, gnms + l * kH,
        tW + (size_t)l * 2 * kH * kH, tb + l * kH, h);
  }
  hipMemsetAsync(stats, 0, 2 * kT * sizeof(float), stream);
  final_lin<<<nodeBlocks, 256, 0, stream>>>(h, fW, fb, out, stats);
  final_norm<<<nodeBlocks, 256, 0, stream>>>(stats, fgw, fgb, fgms, out);
}